// Round 8
// baseline (163.257 us; speedup 1.0000x reference)
//
#include <hip/hip_runtime.h>

typedef __attribute__((ext_vector_type(8))) short short8;
typedef __attribute__((ext_vector_type(4))) short short4v;
typedef __attribute__((ext_vector_type(4))) float floatx4;

#define MFMA16(a,b,c) __builtin_amdgcn_mfma_f32_16x16x32_bf16((a),(b),(c),0,0,0)

static __device__ __forceinline__ unsigned short f2bf(float f){
    unsigned int u = __float_as_uint(f);
    u = (u + 0x7FFFu + ((u >> 16) & 1u)) >> 16;
    return (unsigned short)u;
}

// async global->LDS, 16 B/lane; lds base wave-uniform, lane i -> base + i*16.
// Per-lane SOURCE address allows XOR-swizzled LDS layouts via source permute.
static __device__ __forceinline__ void async16(const unsigned short* g, const unsigned short* l){
    __builtin_amdgcn_global_load_lds(
        (const __attribute__((address_space(1))) unsigned int*)g,
        (__attribute__((address_space(3))) unsigned int*)l, 16, 0, 0);
}

// ---------------------------------------------------------------------------
// Kernel 1: prep = transpose x + convert both weight matrices to bf16.
// ---------------------------------------------------------------------------
__global__ __launch_bounds__(256) void k_prep(const float* __restrict__ x,
                                              unsigned short* __restrict__ xT,
                                              const float* __restrict__ qkvw,
                                              unsigned short* __restrict__ wqkv,
                                              const float* __restrict__ outw,
                                              unsigned short* __restrict__ wout){
    __shared__ unsigned short tile[64][72];
    const int bid = blockIdx.x;
    const int tid = threadIdx.x;
    if (bid < 2048){
        const int c0 = (bid & 7) * 64;
        const int n0 = ((bid >> 3) & 3) * 64;
        const int b  = bid >> 5;
        const int chunk = tid & 7;
        const int r     = tid >> 3;
        const float*    src = x  + (size_t)b * 131072;
        unsigned short* dst = xT + (size_t)b * 131072;
#pragma unroll
        for (int it = 0; it < 2; ++it){
            int c = r + it * 32;
            const float* p = src + (size_t)(c0 + c) * 256 + n0 + chunk * 8;
            float4 f0 = *(const float4*)(p);
            float4 f1 = *(const float4*)(p + 4);
            short8 v;
            v[0]=(short)f2bf(f0.x); v[1]=(short)f2bf(f0.y); v[2]=(short)f2bf(f0.z); v[3]=(short)f2bf(f0.w);
            v[4]=(short)f2bf(f1.x); v[5]=(short)f2bf(f1.y); v[6]=(short)f2bf(f1.z); v[7]=(short)f2bf(f1.w);
            *(short8*)&tile[c][chunk * 8] = v;
        }
        __syncthreads();
#pragma unroll
        for (int it = 0; it < 2; ++it){
            int n = r + it * 32;
            short8 o;
#pragma unroll
            for (int e = 0; e < 8; ++e) o[e] = (short)tile[chunk * 8 + e][n];
            *(short8*)(dst + (size_t)(n0 + n) * 512 + c0 + chunk * 8) = o;
        }
    } else {
        int i = (bid - 2048) * 256 + tid;
        const float* s; unsigned short* d; int j;
        if (i < 196608){ s = qkvw; d = wqkv; j = i; }
        else { j = i - 196608; if (j >= 65536) return; s = outw; d = wout; }
        float4 f = *(const float4*)(s + (size_t)j * 4);
        uint2 v;
        v.x = (unsigned int)f2bf(f.x) | ((unsigned int)f2bf(f.y) << 16);
        v.y = (unsigned int)f2bf(f.z) | ((unsigned int)f2bf(f.w) << 16);
        *(uint2*)(d + (size_t)j * 4) = v;
    }
}

// ---------------------------------------------------------------------------
// Kernel 2: FUSED qkv-projection + attention, one block per (b, h).
// Phase A: BK=128 (4 K-iters, half the barrier drains); Q/K/V LDS OVERLAYS
// the X/W staging region (dead after the K-loop). XOR-8 chunk swizzle
// everywhere; V epilogue uses packed b64 stores; rel pre-scaled by log2(e).
// ---------------------------------------------------------------------------
__global__ __launch_bounds__(512, 2) void k_fused(const unsigned short* __restrict__ xT,
                                                  const unsigned short* __restrict__ wbf,
                                                  const float* __restrict__ qkvb,
                                                  const float* __restrict__ rel,
                                                  unsigned short* __restrict__ ao){
    __shared__ unsigned short SH[59266];          // 118,532 B
    // staging (phase A): X 256x128 @0 (32768), W 192x128 @32768 (24576)
    // overlay (phase B): Q 256x64 @0, K 256x64 @16384, V 64x256 @32768
    const int XS = 0, WS = 32768;
    const int QS = 0, KS = 16384, VS = 32768;
    float* Relsh = (float*)&SH[57344];            // 961 fp32

    const int bid  = blockIdx.x;
    const int xcd  = bid & 7;
    const int slot = bid >> 3;
    const int b = xcd * 8 + (slot & 7);
    const int h = slot >> 3;
    const int tid  = threadIdx.x;
    const int wave = tid >> 6;
    const int lane = tid & 63;
    const int lrow = lane & 15;
    const int lgrp = lane >> 4;
    const int mq = wave >> 1;                     // M-quarter (64 tokens)
    const int nh = wave & 1;                      // N-half (96 cols)

    for (int i = tid; i < 961; i += 512) Relsh[i] = rel[h * 961 + i] * 1.44269504f;

    // ---- phase A: QKV mini-GEMM, BK=128 -----------------------------------
    floatx4 acc[4][6];
#pragma unroll
    for (int i = 0; i < 4; ++i)
#pragma unroll
        for (int j = 0; j < 6; ++j){ floatx4 z = {0.f,0.f,0.f,0.f}; acc[i][j] = z; }

    const unsigned short* xb = xT + (size_t)(b * 256) * 512;
    int xoff[8], xdst[8];
#pragma unroll
    for (int c = 0; c < 8; ++c){
        int s   = (c * 8 + wave) * 64 + lane;     // 0..4095
        int row = s >> 4, pch = s & 15;
        int sch = (pch & 8) | ((pch & 7) ^ (row & 7));
        xoff[c] = row * 512 + sch * 8;
        xdst[c] = XS + (c * 8 + wave) * 512;
    }
    int woff[6], wdst[6];
#pragma unroll
    for (int c = 0; c < 6; ++c){
        int s   = (c * 8 + wave) * 64 + lane;     // 0..3071
        int row = s >> 4, pch = s & 15;
        int sch = (pch & 8) | ((pch & 7) ^ (row & 7));
        int grow = (row >> 6) * 512 + h * 64 + (row & 63);
        woff[c] = grow * 512 + sch * 8;
        wdst[c] = WS + (c * 8 + wave) * 512;
    }

    for (int kk = 0; kk < 512; kk += 128){
#pragma unroll
        for (int c = 0; c < 8; ++c) async16(xb + xoff[c] + kk, &SH[xdst[c]]);
#pragma unroll
        for (int c = 0; c < 6; ++c) async16(wbf + woff[c] + kk, &SH[wdst[c]]);
        __syncthreads();
#pragma unroll
        for (int ks = 0; ks < 4; ++ks){
            short8 af[4], bf[6];
#pragma unroll
            for (int mt = 0; mt < 4; ++mt){
                int row = mq * 64 + mt * 16 + lrow;
                int idx = ks * 4 + lgrp;
                int phys = (idx & 8) | ((idx & 7) ^ (row & 7));
                af[mt] = *(const short8*)&SH[XS + row * 128 + phys * 8];
            }
#pragma unroll
            for (int nt = 0; nt < 6; ++nt){
                int row = nh * 96 + nt * 16 + lrow;
                int idx = ks * 4 + lgrp;
                int phys = (idx & 8) | ((idx & 7) ^ (row & 7));
                bf[nt] = *(const short8*)&SH[WS + row * 128 + phys * 8];
            }
#pragma unroll
            for (int mt = 0; mt < 4; ++mt)
#pragma unroll
                for (int nt = 0; nt < 6; ++nt)
                    acc[mt][nt] = MFMA16(af[mt], bf[nt], acc[mt][nt]);
        }
        __syncthreads();
    }

    // epilogue A: +bias, bf16, scatter into Q/K/V overlay (staging now dead)
#pragma unroll
    for (int mt = 0; mt < 4; ++mt){
        int tk0 = mq * 64 + mt * 16 + lgrp * 4;   // 4 contiguous tokens
#pragma unroll
        for (int nt = 0; nt < 6; ++nt){
            int col = nh * 96 + nt * 16 + lrow;
            int seg = col >> 6, off = col & 63;
            float bv = qkvb[seg * 512 + h * 64 + off];
            if (seg == 2){
                int lch = tk0 >> 3;
                int pch = (lch & 24) | ((lch & 7) ^ (off & 7));
                short4v v4;
#pragma unroll
                for (int r = 0; r < 4; ++r) v4[r] = (short)f2bf(acc[mt][nt][r] + bv);
                *(short4v*)&SH[VS + off * 256 + pch * 8 + (tk0 & 7)] = v4;
            } else {
                int base = seg ? KS : QS;
#pragma unroll
                for (int r = 0; r < 4; ++r){
                    int token = tk0 + r;
                    int pch = (off >> 3) ^ (token & 7);
                    SH[base + token * 64 + pch * 8 + (off & 7)] = f2bf(acc[mt][nt][r] + bv);
                }
            }
        }
    }
    __syncthreads();

    // ---- phase B: attention -----------------------------------------------
    short8 aq[2][2];
#pragma unroll
    for (int pp = 0; pp < 2; ++pp)
#pragma unroll
        for (int kc = 0; kc < 2; ++kc){
            int row = wave * 32 + pp * 16 + lrow;
            int pch = (kc * 4 + lgrp) ^ (row & 7);
            aq[pp][kc] = *(const short8*)&SH[QS + row * 64 + pch * 8];
        }

    floatx4 s2[2][16];
#pragma unroll
    for (int ct = 0; ct < 16; ++ct){              // K frags read ONCE, used by both pp
        int row = ct * 16 + lrow;
        int pch0 = lgrp ^ (row & 7);
        short8 b0 = *(const short8*)&SH[KS + row * 64 + pch0 * 8];
        short8 b1 = *(const short8*)&SH[KS + row * 64 + (pch0 ^ 4) * 8];
        floatx4 z0 = {0.f,0.f,0.f,0.f}, z1 = {0.f,0.f,0.f,0.f};
        z0 = MFMA16(aq[0][0], b0, z0);
        z0 = MFMA16(aq[0][1], b1, z0);
        z1 = MFMA16(aq[1][0], b0, z1);
        z1 = MFMA16(aq[1][1], b1, z1);
        s2[0][ct] = z0;
        s2[1][ct] = z1;
    }

    float inv[2][4];
#pragma unroll
    for (int pp = 0; pp < 2; ++pp)
#pragma unroll
        for (int r = 0; r < 4; ++r){
            int n   = wave * 32 + pp * 16 + lgrp * 4 + r;
            int nh_ = n >> 4, nw = n & 15;
            const float* rbase = Relsh + (nh_ + 15) * 31 + (nw - lrow + 15);
            float sum = 0.f;
#pragma unroll
            for (int ct = 0; ct < 16; ++ct){
                // exp2-domain: s*0.125*log2e + rel*log2e (rel pre-scaled)
                float e = exp2f(s2[pp][ct][r] * 0.18033688f + rbase[-ct * 31]);
                s2[pp][ct][r] = e;
                sum += e;
            }
#pragma unroll
            for (int off = 1; off < 16; off <<= 1)
                sum += __shfl_xor(sum, off, 64);
            inv[pp][r] = 1.f / sum;
        }

    __syncthreads();                      // Q,K reads done -> safe to overlay P

    const int PB = QS + wave * 4096;      // per-wave P (16x256), overlays Q/K
    unsigned short* aob = ao + (size_t)(b * 256) * 512 + h * 64;
#pragma unroll
    for (int pp = 0; pp < 2; ++pp){
#pragma unroll
        for (int ct = 0; ct < 16; ++ct)
#pragma unroll
            for (int r = 0; r < 4; ++r){
                int row = lgrp * 4 + r;
                int lch = ct * 2 + (lrow >> 3);
                int pch = (lch & 24) | ((lch & 7) ^ (row & 7));
                SH[PB + row * 256 + pch * 8 + (lrow & 7)] = f2bf(s2[pp][ct][r]);
            }
        short8 pa[8];
#pragma unroll
        for (int ms = 0; ms < 8; ++ms){
            int lch = ms * 4 + lgrp;
            int pch = (lch & 24) | ((lch & 7) ^ (lrow & 7));
            pa[ms] = *(const short8*)&SH[PB + lrow * 256 + pch * 8];
        }
#pragma unroll
        for (int dt = 0; dt < 4; ++dt){
            floatx4 accO = {0.f,0.f,0.f,0.f};
#pragma unroll
            for (int ms = 0; ms < 8; ++ms){
                int row = dt * 16 + lrow;
                int lch = ms * 4 + lgrp;
                int pch = (lch & 24) | ((lch & 7) ^ (row & 7));
                short8 vb = *(const short8*)&SH[VS + row * 256 + pch * 8];
                accO = MFMA16(pa[ms], vb, accO);
            }
#pragma unroll
            for (int r = 0; r < 4; ++r){
                int n = wave * 32 + pp * 16 + lgrp * 4 + r;
                aob[(size_t)n * 512 + dt * 16 + lrow] = f2bf(accO[r] * inv[pp][r]);
            }
        }
    }
}

// ---------------------------------------------------------------------------
// Kernel 3: out projection, BK=128 (4 K-iters) + XOR swizzle + XCD swizzle,
// 2 blocks/CU (64 KB LDS). fp32 out[b,o,n].
// ---------------------------------------------------------------------------
__global__ __launch_bounds__(256, 2) void k_out(const unsigned short* __restrict__ ao,
                                                const unsigned short* __restrict__ wbf,
                                                const float* __restrict__ bias,
                                                float* __restrict__ out){
    __shared__ unsigned short Ash[16384];   // out_w 128x128
    __shared__ unsigned short Bsh[16384];   // ao    128x128
    const int bid  = blockIdx.x;
    const int xcd  = bid & 7;
    const int slot = bid >> 3;
    const int t0 = (xcd * 16 + (slot & 15)) * 128;
    const int o0 = (slot >> 4) * 128;
    const int tid  = threadIdx.x;
    const int wave = tid >> 6;
    const int lane = tid & 63;
    const int lrow = lane & 15;
    const int lgrp = lane >> 4;
    const int wm   = (wave >> 1) * 64;
    const int wn   = (wave & 1) * 64;

    int aoff[8], boff[8], dstoff[8];
#pragma unroll
    for (int c = 0; c < 8; ++c){
        int s   = (c * 4 + wave) * 64 + lane;    // 0..2047
        int row = s >> 4, pch = s & 15;
        int sch = (pch & 8) | ((pch & 7) ^ (row & 7));
        aoff[c] = (o0 + row) * 512 + sch * 8;
        boff[c] = (t0 + row) * 512 + sch * 8;
        dstoff[c] = (c * 4 + wave) * 512;
    }

    floatx4 acc[4][4];
#pragma unroll
    for (int i = 0; i < 4; ++i)
#pragma unroll
        for (int j = 0; j < 4; ++j){ floatx4 z = {0.f,0.f,0.f,0.f}; acc[i][j] = z; }

    for (int kk = 0; kk < 512; kk += 128){
#pragma unroll
        for (int c = 0; c < 8; ++c) async16(wbf + aoff[c] + kk, &Ash[dstoff[c]]);
#pragma unroll
        for (int c = 0; c < 8; ++c) async16(ao  + boff[c] + kk, &Bsh[dstoff[c]]);
        __syncthreads();
#pragma unroll
        for (int ks = 0; ks < 4; ++ks){
            short8 af[4], bf[4];
#pragma unroll
            for (int mt = 0; mt < 4; ++mt){
                int row = wm + mt * 16 + lrow;
                int idx = ks * 4 + lgrp;
                int phys = (idx & 8) | ((idx & 7) ^ (row & 7));
                af[mt] = *(const short8*)&Ash[row * 128 + phys * 8];
            }
#pragma unroll
            for (int nt = 0; nt < 4; ++nt){
                int row = wn + nt * 16 + lrow;
                int idx = ks * 4 + lgrp;
                int phys = (idx & 8) | ((idx & 7) ^ (row & 7));
                bf[nt] = *(const short8*)&Bsh[row * 128 + phys * 8];
            }
#pragma unroll
            for (int mt = 0; mt < 4; ++mt)
#pragma unroll
                for (int nt = 0; nt < 4; ++nt)
                    acc[mt][nt] = MFMA16(af[mt], bf[nt], acc[mt][nt]);
        }
        __syncthreads();
    }
#pragma unroll
    for (int mt = 0; mt < 4; ++mt){
        int orow0 = o0 + wm + mt*16 + lgrp * 4;
#pragma unroll
        for (int nt = 0; nt < 4; ++nt){
            int tcol = t0 + wn + nt*16 + lrow;
            int bb = tcol >> 8, nn = tcol & 255;
#pragma unroll
            for (int r = 0; r < 4; ++r){
                float bv = bias[orow0 + r];
                out[(size_t)(bb * 512 + orow0 + r) * 256 + nn] = acc[mt][nt][r] + bv;
            }
        }
    }
}

// ---------------------------------------------------------------------------
extern "C" void kernel_launch(void* const* d_in, const int* in_sizes, int n_in,
                              void* d_out, int out_size, void* d_ws, size_t ws_size,
                              hipStream_t stream){
    const float* x    = (const float*)d_in[0];
    const float* qkvw = (const float*)d_in[1];
    const float* qkvb = (const float*)d_in[2];
    const float* outw = (const float*)d_in[3];
    const float* outb = (const float*)d_in[4];
    const float* rel  = (const float*)d_in[5];
    float* out = (float*)d_out;

    // workspace: XT (16 MiB) | AO (16 MiB) | weights (2.5 MiB)
    const size_t XT_OFF = 0;
    const size_t AO_OFF = 16777216;
    const size_t W_OFF  = 33554432;
    const size_t NEED   = W_OFF + 4194304;
    if (ws_size < NEED) return;

    char* ws = (char*)d_ws;
    unsigned short* xT = (unsigned short*)(ws + XT_OFF);
    unsigned short* ao = (unsigned short*)(ws + AO_OFF);
    unsigned short* wqkv_bf = (unsigned short*)(ws + W_OFF);
    unsigned short* wout_bf = (unsigned short*)(ws + W_OFF + 2097152);

    hipLaunchKernelGGL(k_prep,  dim3(3072), dim3(256), 0, stream,
                       x, xT, qkvw, wqkv_bf, outw, wout_bf);
    hipLaunchKernelGGL(k_fused, dim3(512),  dim3(512), 0, stream,
                       xT, wqkv_bf, qkvb, rel, ao);
    hipLaunchKernelGGL(k_out,   dim3(512),  dim3(256), 0, stream,
                       ao, wout_bf, outb, out);
}